// Round 13
// baseline (72.261 us; speedup 1.0000x reference)
//
#include <hip/hip_runtime.h>
#include <hip/hip_bf16.h>

typedef __attribute__((ext_vector_type(8))) short bf16x8;
typedef __attribute__((ext_vector_type(8))) _Float16 f16x8;
typedef __attribute__((ext_vector_type(4))) float f32x4;
typedef __attribute__((ext_vector_type(16))) float f32x16;

#define MFMA16B(a, b, c) __builtin_amdgcn_mfma_f32_16x16x32_bf16(a, b, c, 0, 0, 0)
#define MFMA32F(a, b, c) __builtin_amdgcn_mfma_f32_32x32x16_f16(a, b, c, 0, 0, 0)

static constexpr int S = 2048;
static constexpr int D = 128;
static constexpr float LOG2E = 1.4426950408889634f;

// ---------------- helpers ----------------
__device__ inline unsigned short f2b(float f) {      // fp32->bf16 RNE
    union { float f; unsigned int u; } v; v.f = f;
    unsigned int u = v.u;
    return (unsigned short)((u + 0x7FFFu + ((u >> 16) & 1u)) >> 16);
}
__device__ inline float b2f(unsigned short h) {
    union { unsigned int u; float f; } v; v.u = ((unsigned int)h) << 16;
    return v.f;
}
__device__ inline unsigned int pack2(float a, float b) {
    return (unsigned int)f2b(a) | ((unsigned int)f2b(b) << 16);
}
__device__ inline unsigned int pkh(float a, float b) {  // fp32->fp16 RNE pair
    union { _Float16 h; unsigned short u; } ua, ub;
    ua.h = (_Float16)a; ub.h = (_Float16)b;
    return (unsigned int)ua.u | ((unsigned int)ub.u << 16);
}

// async 16B/lane global->LDS copy (CK-style integer AS reinterpret)
__device__ __forceinline__ void gload16(const void* g, void* l) {
    __builtin_amdgcn_global_load_lds(
        (const __attribute__((address_space(1))) unsigned int*)(unsigned long long)(g),
        (__attribute__((address_space(3))) unsigned int*)(unsigned int)(unsigned long long)(l),
        16, 0, 0);
}

// ---------------- prep: fp32 -> fp16 images for the 32x32 MFMA kernel ------------
// ws (ushort units): [mat(0=X,1=Y)][role(0=K,1=VT)], each 8*S*D elems.
// Per (b, t32) tile (8 KB each, 64 tiles per b):
//   K  image: byte(j,d pair cp) = j*256 + cp*4,   XOR ((j&7)<<4)   (j=0..31, cp=0..63)
//   VT image: byte(d, j pair jp) = d*64 + jp*4,   XOR ((d&7)<<4)   (d=0..127, jp=0..15)
__global__ __launch_bounds__(256) void bimodal_prep5(
    const float* __restrict__ X, const float* __restrict__ Y,
    unsigned short* __restrict__ WS)
{
    const int bid = blockIdx.x;          // [mat(2)][b(8)][t(64)]
    const int t = bid & 63;
    const int b = (bid >> 6) & 7;
    const int mat = bid >> 9;
    const float* src = mat ? Y : X;
    char* kf = (char*)(WS + (size_t)(mat * 2 + 0) * (8ull * S * D)) + (size_t)(b * 64 + t) * 8192;
    char* vt = (char*)(WS + (size_t)(mat * 2 + 1) * (8ull * S * D)) + (size_t)(b * 64 + t) * 8192;

    __shared__ float ftile[32][129];
    const int tid = threadIdx.x;
    const float* tsrc = src + ((size_t)(b * S + t * 32)) * D;
#pragma unroll
    for (int it = 0; it < 4; ++it) {
        int idx = tid + it * 256;        // 1024 float4 chunks
        int row = idx >> 5, ch = idx & 31;
        float4 v = *(const float4*)(tsrc + (size_t)row * D + ch * 4);
        ftile[row][ch * 4 + 0] = v.x; ftile[row][ch * 4 + 1] = v.y;
        ftile[row][ch * 4 + 2] = v.z; ftile[row][ch * 4 + 3] = v.w;
    }
    __syncthreads();
#pragma unroll
    for (int it = 0; it < 8; ++it) {
        int w = tid + it * 256;          // 2048 dwords: K row-major
        int row = w >> 6, cp = w & 63;
        unsigned int d = pkh(ftile[row][2 * cp], ftile[row][2 * cp + 1]);
        int byte = (row * 256 + cp * 4) ^ ((row & 7) << 4);
        *(unsigned int*)(kf + byte) = d;
    }
#pragma unroll
    for (int it = 0; it < 8; ++it) {
        int w = tid + it * 256;          // 2048 dwords: V transposed
        int dd = w >> 4, jp = w & 15;
        unsigned int d = pkh(ftile[2 * jp][dd], ftile[2 * jp + 1][dd]);
        int byte = (dd * 64 + jp * 4) ^ ((dd & 7) << 4);
        *(unsigned int*)(vt + byte) = d;
    }
}

// ---------------- main: 32x32x16 swapped-QK^T flash attn, counted-vmcnt pipeline ----
// 256 blocks x 512 threads (8 waves). Waves 0-3 (grp 0): tiles 0..31;
// waves 4-7 (grp 1): tiles 32..63. 16 pair-steps; flash-combine (wv, wv^4).
// Softmax runs in exp2 domain (Q pre-scaled by log2e).
__global__ __launch_bounds__(512) void bimodal_attn_v8(
    const float* __restrict__ X, const float* __restrict__ Y,
    const unsigned short* __restrict__ WS, float* __restrict__ Out)
{
    const int orig = blockIdx.x;
    const int wg = (orig & 7) * 32 + (orig >> 3);   // XCD-aware swizzle (256 = 8*32)
    const int qt = wg & 15;
    const int p  = (wg >> 4) & 1;
    const int b  = wg >> 5;

    const float* Q = p ? Y : X;
    const int kvmat = p ? 0 : 1;
    const int ocol = p * D;

    __shared__ __align__(16) char smem[131072];  // 2 grp x 2 buf x (K0|K1|V0|V1 = 32 KB)

    const int tid = threadIdx.x;
    const int wv = tid >> 6;
    const int lane = tid & 63;
    const int qp = lane & 31;          // q column / A-frag row
    const int h = lane >> 5;           // lane half
    const int grp = wv >> 2;           // KV group
    const int qb = wv & 3;             // q-block
    const int i0 = qt * 128 + qb * 32;

    // Q B-frags (32x32x16), pre-scaled by log2e: lane supplies Q[qp][16*kc + 8*h + i]
    const float* qrow = Q + ((size_t)(b * S + i0 + qp)) * D;
    f16x8 qf[8];
#pragma unroll
    for (int kc = 0; kc < 8; ++kc) {
        const float* qpp = qrow + kc * 16 + h * 8;
        float4 f0 = *(const float4*)qpp;
        float4 f1 = *(const float4*)(qpp + 4);
        f16x8 tq;
        tq[0] = (_Float16)(f0.x * LOG2E); tq[1] = (_Float16)(f0.y * LOG2E);
        tq[2] = (_Float16)(f0.z * LOG2E); tq[3] = (_Float16)(f0.w * LOG2E);
        tq[4] = (_Float16)(f1.x * LOG2E); tq[5] = (_Float16)(f1.y * LOG2E);
        tq[6] = (_Float16)(f1.z * LOG2E); tq[7] = (_Float16)(f1.w * LOG2E);
        qf[kc] = tq;
    }

    f32x16 o[4];
#pragma unroll
    for (int db = 0; db < 4; ++db)
#pragma unroll
        for (int i = 0; i < 16; ++i) o[db][i] = 0.f;
    float m = -1e30f, l = 0.f;

    const char* kfb = (const char*)(WS + (size_t)(kvmat * 2 + 0) * (8ull * S * D)) + (size_t)b * (S * D * 2);
    const char* vtb = (const char*)(WS + (size_t)(kvmat * 2 + 1) * (8ull * S * D)) + (size_t)b * (S * D * 2);
    const int gl = qb * 64 + lane;     // 0..255 within group
    char* mybase = smem + grp * 65536;

    auto stage = [&](int ps, int bi) {
        char* kb = mybase + bi * 32768;
        const char* kt = kfb + (size_t)(32 * grp + 2 * ps) * 8192;   // 16 KB (2 K tiles)
        const char* vp = vtb + (size_t)(32 * grp + 2 * ps) * 8192;   // 16 KB (2 V tiles)
#pragma unroll
        for (int i = 0; i < 4; ++i)
            gload16(kt + gl * 16 + i * 4096, kb + gl * 16 + i * 4096);
#pragma unroll
        for (int i = 0; i < 4; ++i)
            gload16(vp + gl * 16 + i * 4096, kb + 16384 + gl * 16 + i * 4096);
    };

    auto qkt = [&](const char* kb) {
        f32x16 sT;
#pragma unroll
        for (int i = 0; i < 16; ++i) sT[i] = 0.f;
#pragma unroll
        for (int kc = 0; kc < 8; ++kc) {
            int byte = (qp * 256 + kc * 32 + h * 16) ^ ((qp & 7) << 4);
            f16x8 kA = *(const f16x8*)(kb + byte);
            sT = MFMA32F(kA, qf[kc], sT);
        }
        return sT;
    };

    auto smpv = [&](f32x16& sT, const char* vb) {
        float pmax = sT[0];
#pragma unroll
        for (int i = 1; i < 16; ++i) pmax = fmaxf(pmax, sT[i]);
        pmax = fmaxf(pmax, __shfl_xor(pmax, 32));
        if (!__all(pmax - m <= 11.5f)) {     // T13 defer-max (log2 domain)
            float mn = fmaxf(m, pmax);
            float alpha = exp2f(m - mn);
            m = mn; l *= alpha;
#pragma unroll
            for (int db = 0; db < 4; ++db)
#pragma unroll
                for (int i = 0; i < 16; ++i) o[db][i] *= alpha;
        }
        float rs = 0.f;
#pragma unroll
        for (int i = 0; i < 16; ++i) { sT[i] = exp2f(sT[i] - m); rs += sT[i]; }
        rs += __shfl_xor(rs, 32);
        l += rs;

        // pack P pairs; build PV B-frags with permlane32_swap (T12)
        unsigned w8[8];
#pragma unroll
        for (int t2 = 0; t2 < 4; ++t2) {
            w8[2 * t2]     = pkh(sT[4 * t2 + 0], sT[4 * t2 + 1]);
            w8[2 * t2 + 1] = pkh(sT[4 * t2 + 2], sT[4 * t2 + 3]);
        }
        union { unsigned u[4]; f16x8 v; } bf0, bf1;
#pragma unroll
        for (int v2 = 0; v2 < 2; ++v2) {
            unsigned a0 = w8[v2], b0 = w8[2 + v2];
            asm volatile("v_permlane32_swap_b32 %0, %1" : "+v"(a0), "+v"(b0));
            bf0.u[v2] = a0; bf0.u[2 + v2] = b0;
            unsigned a1 = w8[4 + v2], b1 = w8[6 + v2];
            asm volatile("v_permlane32_swap_b32 %0, %1" : "+v"(a1), "+v"(b1));
            bf1.u[v2] = a1; bf1.u[2 + v2] = b1;
        }

        __builtin_amdgcn_s_setprio(1);
#pragma unroll
        for (int db = 0; db < 4; ++db) {
            int rowbyte = (db * 32 + qp) * 64;
            int x0 = (rowbyte + h * 16) ^ ((qp & 7) << 4);
            int x1 = (rowbyte + 32 + h * 16) ^ ((qp & 7) << 4);
            f16x8 v0 = *(const f16x8*)(vb + x0);
            f16x8 v1 = *(const f16x8*)(vb + x1);
            o[db] = MFMA32F(v0, bf0.v, o[db]);
            o[db] = MFMA32F(v1, bf1.v, o[db]);
        }
        __builtin_amdgcn_s_setprio(0);
    };

    // ---- prologue: stage pair 0 ----
    stage(0, 0);

    for (int s = 0; s < 16; ++s) {
        // T3/T4: issue next pair, then counted-vmcnt gate (pair s done; s+1 in flight)
        if (s < 15) {
            stage(s + 1, (s + 1) & 1);
            asm volatile("s_waitcnt vmcnt(8)" ::: "memory");
        } else {
            asm volatile("s_waitcnt vmcnt(0)" ::: "memory");
        }
        __builtin_amdgcn_s_barrier();
        __builtin_amdgcn_sched_barrier(0);

        const char* kb = mybase + (s & 1) * 32768;

        __builtin_amdgcn_s_setprio(1);
        f32x16 s0 = qkt(kb);            // tile 2s
        f32x16 s1 = qkt(kb + 8192);     // tile 2s+1
        __builtin_amdgcn_s_setprio(0);

        smpv(s0, kb + 16384);           // SM(t0) overlaps QK(t1) MFMAs; PV(t0)
        smpv(s1, kb + 24576);           // SM(t1) overlaps PV(t0) MFMAs; PV(t1)

        // protect buffer: all waves done reading before next-iter stage overwrites
        __builtin_amdgcn_sched_barrier(0);
        __builtin_amdgcn_s_barrier();
    }

    // ---- flash-combine across wave pairs (wv, wv^4); m,l in log2 domain ----
    {
        float2* mlp = (float2*)(smem + wv * 512);
        mlp[lane] = make_float2(m, l);
    }
    __syncthreads();
    float2 pml = ((float2*)(smem + (wv ^ 4) * 512))[lane];
    float mstar = fmaxf(m, pml.x);
    float sc = exp2f(m - mstar);
    float lstar = sc * l + exp2f(pml.x - mstar) * pml.y;
#pragma unroll
    for (int db = 0; db < 4; ++db)
#pragma unroll
        for (int i = 0; i < 16; ++i) o[db][i] *= sc;
    __syncthreads();

    // conflict-free transposed exchange: ob[qb][i][lane]
    float* ob = (float*)(smem + 4096);
#pragma unroll
    for (int db = 0; db < 4; ++db) {
        if (grp == 1) {
#pragma unroll
            for (int i = 0; i < 16; ++i) ob[qb * 1024 + i * 64 + lane] = o[db][i];
        }
        __syncthreads();
        if (grp == 0) {
#pragma unroll
            for (int i = 0; i < 16; ++i) o[db][i] += ob[qb * 1024 + i * 64 + lane];
        }
        __syncthreads();
    }

    // ---- epilogue (group 0 only): normalize, gate by Q, float4 stores ----
    if (grp == 0) {
        const float invl = 1.f / lstar;
        float* outr = Out + ((size_t)(b * S + i0 + qp)) * (2 * D) + ocol;
#pragma unroll
        for (int db = 0; db < 4; ++db)
#pragma unroll
            for (int t2 = 0; t2 < 4; ++t2) {
                int d0 = db * 32 + t2 * 8 + h * 4;
                float4 qv = *(const float4*)(qrow + d0);
                float4 ov;
                ov.x = o[db][4 * t2 + 0] * invl * qv.x;
                ov.y = o[db][4 * t2 + 1] * invl * qv.y;
                ov.z = o[db][4 * t2 + 2] * invl * qv.z;
                ov.w = o[db][4 * t2 + 3] * invl * qv.w;
                *(float4*)(outr + d0) = ov;
            }
    }
}

// ---------------- fallback (round-2 verified kernel, no workspace needed) ----------------
__global__ __launch_bounds__(256) void bimodal_attn_fb(
    const float* __restrict__ X, const float* __restrict__ Y,
    float* __restrict__ Out)
{
    const int bid = blockIdx.x;
    const int qt = bid & 31;
    const int p  = (bid >> 5) & 1;
    const int b  = bid >> 6;

    const float* Q  = p ? Y : X;
    const float* KV = p ? X : Y;
    const int ocol = p * D;

    __shared__ unsigned short Khi[64 * D];
    __shared__ unsigned short Klo[64 * D];
    __shared__ unsigned short Vt[D * 64];
    __shared__ unsigned short Psh[4][16 * 72];

    const int tid = threadIdx.x;
    const int wv = tid >> 6;
    const int lane = tid & 63;
    const int c = lane & 15;
    const int g = lane >> 4;
    const int i0 = qt * 64 + wv * 16;

    const float* qbase = Q + ((size_t)(b * S + i0 + c)) * D;
    bf16x8 qhi[4], qlo[4];
#pragma unroll
    for (int kc = 0; kc < 4; ++kc) {
        const float* qp = qbase + kc * 32 + g * 8;
        float4 f0 = *(const float4*)qp;
        float4 f1 = *(const float4*)(qp + 4);
        float fv[8] = {f0.x, f0.y, f0.z, f0.w, f1.x, f1.y, f1.z, f1.w};
        bf16x8 th, tl;
#pragma unroll
        for (int i = 0; i < 8; ++i) {
            unsigned short hh = f2b(fv[i]);
            th[i] = (short)hh;
            tl[i] = (short)f2b(fv[i] - b2f(hh));
        }
        qhi[kc] = th; qlo[kc] = tl;
    }

    f32x4 o[8];
#pragma unroll
    for (int nb = 0; nb < 8; ++nb) { o[nb][0] = 0.f; o[nb][1] = 0.f; o[nb][2] = 0.f; o[nb][3] = 0.f; }
    float m[4], l[4];
#pragma unroll
    for (int r = 0; r < 4; ++r) { m[r] = -1e30f; l[r] = 0.f; }

    const float* kvb = KV + (size_t)b * S * D;
    unsigned short* pbuf = Psh[wv];

    for (int j0 = 0; j0 < S; j0 += 64) {
#pragma unroll
        for (int t = 0; t < 4; ++t) {
            int task = tid + t * 256;
            int jr = task >> 4, sl = task & 15;
            const float* src = kvb + (size_t)(j0 + jr) * D + sl * 8;
            float4 f0 = *(const float4*)src;
            float4 f1 = *(const float4*)(src + 4);
            float fv[8] = {f0.x, f0.y, f0.z, f0.w, f1.x, f1.y, f1.z, f1.w};
            unsigned short hv[8];
            float lv[8];
#pragma unroll
            for (int i = 0; i < 8; ++i) {
                hv[i] = f2b(fv[i]);
                lv[i] = fv[i] - b2f(hv[i]);
            }
            uint4 wh, wl;
            wh.x = (unsigned int)hv[0] | ((unsigned int)hv[1] << 16);
            wh.y = (unsigned int)hv[2] | ((unsigned int)hv[3] << 16);
            wh.z = (unsigned int)hv[4] | ((unsigned int)hv[5] << 16);
            wh.w = (unsigned int)hv[6] | ((unsigned int)hv[7] << 16);
            wl.x = pack2(lv[0], lv[1]); wl.y = pack2(lv[2], lv[3]);
            wl.z = pack2(lv[4], lv[5]); wl.w = pack2(lv[6], lv[7]);
            int byte = (jr * 256 + sl * 16) ^ ((jr & 7) << 4);
            *(uint4*)((char*)Khi + byte) = wh;
            *(uint4*)((char*)Klo + byte) = wl;
        }
#pragma unroll
        for (int t = 0; t < 2; ++t) {
            int task = tid + t * 256;
            int jp = task & 31, dc = task >> 5;
            const float* s0 = kvb + (size_t)(j0 + 2 * jp) * D + dc * 8;
            const float* s1 = s0 + D;
            float4 a0 = *(const float4*)s0, a1 = *(const float4*)(s0 + 4);
            float4 b0 = *(const float4*)s1, b1 = *(const float4*)(s1 + 4);
            float av[8] = {a0.x, a0.y, a0.z, a0.w, a1.x, a1.y, a1.z, a1.w};
            float bv[8] = {b0.x, b0.y, b0.z, b0.w, b1.x, b1.y, b1.z, b1.w};
#pragma unroll
            for (int i = 0; i < 8; ++i) {
                int d = dc * 8 + i;
                int byte = (d * 128 + jp * 4) ^ ((d & 7) << 4);
                *(unsigned int*)((char*)Vt + byte) = pack2(av[i], bv[i]);
            }
        }
        __syncthreads();

        f32x4 sF[4];
#pragma unroll
        for (int nb = 0; nb < 4; ++nb) {
            f32x4 acc; acc[0] = 0.f; acc[1] = 0.f; acc[2] = 0.f; acc[3] = 0.f;
#pragma unroll
            for (int kc = 0; kc < 4; ++kc) {
                int row = nb * 16 + c;
                int byte = (row * 256 + (kc * 32 + g * 8) * 2) ^ ((row & 7) << 4);
                bf16x8 kh = *(const bf16x8*)((char*)Khi + byte);
                bf16x8 kl = *(const bf16x8*)((char*)Klo + byte);
                acc = MFMA16B(qhi[kc], kh, acc);
                acc = MFMA16B(qhi[kc], kl, acc);
                acc = MFMA16B(qlo[kc], kh, acc);
            }
            sF[nb] = acc;
        }

#pragma unroll
        for (int r = 0; r < 4; ++r) {
            float v = fmaxf(fmaxf(sF[0][r], sF[1][r]), fmaxf(sF[2][r], sF[3][r]));
            v = fmaxf(v, __shfl_xor(v, 1));
            v = fmaxf(v, __shfl_xor(v, 2));
            v = fmaxf(v, __shfl_xor(v, 4));
            v = fmaxf(v, __shfl_xor(v, 8));
            float mn = fmaxf(m[r], v);
            float alpha = __expf(m[r] - mn);
            m[r] = mn;
            float rs = 0.f;
#pragma unroll
            for (int nb = 0; nb < 4; ++nb) {
                float pv = __expf(sF[nb][r] - mn);
                sF[nb][r] = pv;
                rs += pv;
            }
            rs += __shfl_xor(rs, 1);
            rs += __shfl_xor(rs, 2);
            rs += __shfl_xor(rs, 4);
            rs += __shfl_xor(rs, 8);
            l[r] = l[r] * alpha + rs;
#pragma unroll
            for (int nb = 0; nb < 8; ++nb) o[nb][r] *= alpha;
        }

#pragma unroll
        for (int nb = 0; nb < 4; ++nb)
#pragma unroll
            for (int r = 0; r < 4; ++r)
                pbuf[(g * 4 + r) * 72 + nb * 16 + c] = f2b(sF[nb][r]);

        bf16x8 pa[2];
#pragma unroll
        for (int kc = 0; kc < 2; ++kc)
            pa[kc] = *(const bf16x8*)(pbuf + c * 72 + kc * 32 + g * 8);

#pragma unroll
        for (int nb = 0; nb < 8; ++nb) {
#pragma unroll
            for (int kc = 0; kc < 2; ++kc) {
                int d = nb * 16 + c;
                int byte = (d * 128 + (kc * 32 + g * 8) * 2) ^ ((d & 7) << 4);
                bf16x8 vf = *(const bf16x8*)((char*)Vt + byte);
                o[nb] = MFMA16B(pa[kc], vf, o[nb]);
            }
        }
        __syncthreads();
    }

    float* outb = Out + ((size_t)(b * S + i0)) * (2 * D) + ocol;
    const float* qg = Q + (size_t)(b * S + i0) * D;
#pragma unroll
    for (int r = 0; r < 4; ++r) {
        int row = g * 4 + r;
        float inv = 1.f / l[r];
#pragma unroll
        for (int nb = 0; nb < 8; ++nb) {
            int col = nb * 16 + c;
            float qv = qg[(size_t)row * D + col];
            outb[(size_t)row * (2 * D) + col] = o[nb][r] * inv * qv;
        }
    }
}

extern "C" void kernel_launch(void* const* d_in, const int* in_sizes, int n_in,
                              void* d_out, int out_size, void* d_ws, size_t ws_size,
                              hipStream_t stream) {
    const float* x = (const float*)d_in[0];
    const float* y = (const float*)d_in[1];
    float* out = (float*)d_out;
    const size_t need = 4ull * 8 * S * D * 2;   // 16 MB fp16 staging
    if (ws_size >= need) {
        hipLaunchKernelGGL(bimodal_prep5, dim3(1024), dim3(256), 0, stream,
                           x, y, (unsigned short*)d_ws);
        hipLaunchKernelGGL(bimodal_attn_v8, dim3(256), dim3(512), 0, stream,
                           x, y, (const unsigned short*)d_ws, out);
    } else {
        hipLaunchKernelGGL(bimodal_attn_fb, dim3(512), dim3(256), 0, stream, x, y, out);
    }
}

// Round 14
// 67.425 us; speedup vs baseline: 1.0717x; 1.0717x over previous
//
#include <hip/hip_runtime.h>
#include <hip/hip_bf16.h>

typedef __attribute__((ext_vector_type(8))) short bf16x8;
typedef __attribute__((ext_vector_type(8))) _Float16 f16x8;
typedef __attribute__((ext_vector_type(4))) float f32x4;
typedef __attribute__((ext_vector_type(16))) float f32x16;

#define MFMA16B(a, b, c) __builtin_amdgcn_mfma_f32_16x16x32_bf16(a, b, c, 0, 0, 0)
#define MFMA32F(a, b, c) __builtin_amdgcn_mfma_f32_32x32x16_f16(a, b, c, 0, 0, 0)

static constexpr int S = 2048;
static constexpr int D = 128;

// ---------------- helpers ----------------
__device__ inline unsigned short f2b(float f) {      // fp32->bf16 RNE
    union { float f; unsigned int u; } v; v.f = f;
    unsigned int u = v.u;
    return (unsigned short)((u + 0x7FFFu + ((u >> 16) & 1u)) >> 16);
}
__device__ inline float b2f(unsigned short h) {
    union { unsigned int u; float f; } v; v.u = ((unsigned int)h) << 16;
    return v.f;
}
__device__ inline unsigned int pack2(float a, float b) {
    return (unsigned int)f2b(a) | ((unsigned int)f2b(b) << 16);
}
__device__ inline unsigned int pkh(float a, float b) {  // fp32->fp16 RNE pair
    union { _Float16 h; unsigned short u; } ua, ub;
    ua.h = (_Float16)a; ub.h = (_Float16)b;
    return (unsigned int)ua.u | ((unsigned int)ub.u << 16);
}

// async 16B/lane global->LDS copy (CK-style integer AS reinterpret)
__device__ __forceinline__ void gload16(const void* g, void* l) {
    __builtin_amdgcn_global_load_lds(
        (const __attribute__((address_space(1))) unsigned int*)(unsigned long long)(g),
        (__attribute__((address_space(3))) unsigned int*)(unsigned int)(unsigned long long)(l),
        16, 0, 0);
}

// ---------------- prep: fp32 -> fp16 images for the 32x32 MFMA kernel ------------
// ws (ushort units): [mat(0=X,1=Y)][role(0=K,1=VT)], each 8*S*D elems.
// Per (b, t32) tile (8 KB each, 64 tiles per b):
//   K  image: byte(j,d pair cp) = j*256 + cp*4,   XOR ((j&7)<<4)   (j=0..31, cp=0..63)
//   VT image: byte(d, j pair jp) = d*64 + jp*4,   XOR ((d&7)<<4)   (d=0..127, jp=0..15)
__global__ __launch_bounds__(256) void bimodal_prep5(
    const float* __restrict__ X, const float* __restrict__ Y,
    unsigned short* __restrict__ WS)
{
    const int bid = blockIdx.x;          // [mat(2)][b(8)][t(64)]
    const int t = bid & 63;
    const int b = (bid >> 6) & 7;
    const int mat = bid >> 9;
    const float* src = mat ? Y : X;
    char* kf = (char*)(WS + (size_t)(mat * 2 + 0) * (8ull * S * D)) + (size_t)(b * 64 + t) * 8192;
    char* vt = (char*)(WS + (size_t)(mat * 2 + 1) * (8ull * S * D)) + (size_t)(b * 64 + t) * 8192;

    __shared__ float ftile[32][129];
    const int tid = threadIdx.x;
    const float* tsrc = src + ((size_t)(b * S + t * 32)) * D;
#pragma unroll
    for (int it = 0; it < 4; ++it) {
        int idx = tid + it * 256;        // 1024 float4 chunks
        int row = idx >> 5, ch = idx & 31;
        float4 v = *(const float4*)(tsrc + (size_t)row * D + ch * 4);
        ftile[row][ch * 4 + 0] = v.x; ftile[row][ch * 4 + 1] = v.y;
        ftile[row][ch * 4 + 2] = v.z; ftile[row][ch * 4 + 3] = v.w;
    }
    __syncthreads();
#pragma unroll
    for (int it = 0; it < 8; ++it) {
        int w = tid + it * 256;          // 2048 dwords: K row-major
        int row = w >> 6, cp = w & 63;
        unsigned int d = pkh(ftile[row][2 * cp], ftile[row][2 * cp + 1]);
        int byte = (row * 256 + cp * 4) ^ ((row & 7) << 4);
        *(unsigned int*)(kf + byte) = d;
    }
#pragma unroll
    for (int it = 0; it < 8; ++it) {
        int w = tid + it * 256;          // 2048 dwords: V transposed
        int dd = w >> 4, jp = w & 15;
        unsigned int d = pkh(ftile[2 * jp][dd], ftile[2 * jp + 1][dd]);
        int byte = (dd * 64 + jp * 4) ^ ((dd & 7) << 4);
        *(unsigned int*)(vt + byte) = d;
    }
}

// ---------------- main: dual-Q 32x32x16 swapped-QK^T flash attn, kv-split-4 ----
// 256 blocks x 512 threads (8 waves). Wave wv: s = wv&1 (q-position, 64 rows),
// g = wv>>1 (KV group, tiles g*16..g*16+15). Each wave: 2 q-blocks x quarter sweep.
// K/V LDS reads shared across the 2 q-blocks (halved traffic vs v7).
// End: 4-way flash-combine tree across KV groups; waves 0,1 write output.
__global__ __launch_bounds__(512) void bimodal_attn_v9(
    const float* __restrict__ X, const float* __restrict__ Y,
    const unsigned short* __restrict__ WS, float* __restrict__ Out)
{
    const int orig = blockIdx.x;
    const int wg = (orig & 7) * 32 + (orig >> 3);   // XCD-aware swizzle (256 = 8*32)
    const int qt = wg & 15;
    const int p  = (wg >> 4) & 1;
    const int b  = wg >> 5;

    const float* Q = p ? Y : X;
    const int kvmat = p ? 0 : 1;
    const int ocol = p * D;

    __shared__ __align__(16) char smem[131072];  // 4 grp x 2 buf x (K 8K + V 8K)

    const int tid = threadIdx.x;
    const int wv = tid >> 6;
    const int lane = tid & 63;
    const int qp = lane & 31;          // q column / A-frag row
    const int h = lane >> 5;           // lane half
    const int s = wv & 1;              // q position (0/1)
    const int g = wv >> 1;             // KV group (0..3)
    const int i0 = qt * 128 + s * 64;  // wave's first q row (2 blocks of 32)

    // Q B-frags (32x32x16) for both q-blocks: Q[i0 + qb*32 + qp][16*kc + 8*h + i]
    const float* qrow0 = Q + ((size_t)(b * S + i0 + qp)) * D;
    const float* qrow1 = qrow0 + 32 * D;
    f16x8 qf0[8], qf1[8];
#pragma unroll
    for (int kc = 0; kc < 8; ++kc) {
        const float* q0 = qrow0 + kc * 16 + h * 8;
        const float* q1 = qrow1 + kc * 16 + h * 8;
        float4 a0 = *(const float4*)q0, a1 = *(const float4*)(q0 + 4);
        float4 c0 = *(const float4*)q1, c1 = *(const float4*)(q1 + 4);
        f16x8 t0, t1;
        t0[0] = (_Float16)a0.x; t0[1] = (_Float16)a0.y; t0[2] = (_Float16)a0.z; t0[3] = (_Float16)a0.w;
        t0[4] = (_Float16)a1.x; t0[5] = (_Float16)a1.y; t0[6] = (_Float16)a1.z; t0[7] = (_Float16)a1.w;
        t1[0] = (_Float16)c0.x; t1[1] = (_Float16)c0.y; t1[2] = (_Float16)c0.z; t1[3] = (_Float16)c0.w;
        t1[4] = (_Float16)c1.x; t1[5] = (_Float16)c1.y; t1[6] = (_Float16)c1.z; t1[7] = (_Float16)c1.w;
        qf0[kc] = t0; qf1[kc] = t1;
    }

    f32x16 o0[4], o1[4];
#pragma unroll
    for (int db = 0; db < 4; ++db)
#pragma unroll
        for (int i = 0; i < 16; ++i) { o0[db][i] = 0.f; o1[db][i] = 0.f; }
    float m0 = -1e30f, l0 = 0.f, m1 = -1e30f, l1 = 0.f;

    const char* kfb = (const char*)(WS + (size_t)(kvmat * 2 + 0) * (8ull * S * D)) + (size_t)b * (S * D * 2);
    const char* vtb = (const char*)(WS + (size_t)(kvmat * 2 + 1) * (8ull * S * D)) + (size_t)b * (S * D * 2);
    const int gl = s * 64 + lane;      // 0..127 within group (2 waves/group)
    char* mybase = smem + g * 32768;

    auto stage = [&](int t, int bi) {
        char* kb = mybase + bi * 16384;
        const char* kt = kfb + (size_t)(g * 16 + t) * 8192;
        const char* vp = vtb + (size_t)(g * 16 + t) * 8192;
#pragma unroll
        for (int i = 0; i < 4; ++i)
            gload16(kt + gl * 16 + i * 2048, kb + gl * 16 + i * 2048);
#pragma unroll
        for (int i = 0; i < 4; ++i)
            gload16(vp + gl * 16 + i * 2048, kb + 8192 + gl * 16 + i * 2048);
    };

    auto softmax_pack = [&](f32x16& sT, float& m, float& l, f32x16 (&o)[4],
                            f16x8& pb0, f16x8& pb1) {
        float pmax = sT[0];
#pragma unroll
        for (int i = 1; i < 16; ++i) pmax = fmaxf(pmax, sT[i]);
        pmax = fmaxf(pmax, __shfl_xor(pmax, 32));
        if (!__all(pmax - m <= 8.f)) {       // T13 defer-max
            float mn = fmaxf(m, pmax);
            float alpha = __expf(m - mn);
            m = mn; l *= alpha;
#pragma unroll
            for (int db = 0; db < 4; ++db)
#pragma unroll
                for (int i = 0; i < 16; ++i) o[db][i] *= alpha;
        }
        float rs = 0.f;
#pragma unroll
        for (int i = 0; i < 16; ++i) { sT[i] = __expf(sT[i] - m); rs += sT[i]; }
        rs += __shfl_xor(rs, 32);
        l += rs;

        unsigned w8[8];
#pragma unroll
        for (int t2 = 0; t2 < 4; ++t2) {
            w8[2 * t2]     = pkh(sT[4 * t2 + 0], sT[4 * t2 + 1]);
            w8[2 * t2 + 1] = pkh(sT[4 * t2 + 2], sT[4 * t2 + 3]);
        }
        union { unsigned u[4]; f16x8 v; } bf0, bf1;
#pragma unroll
        for (int v2 = 0; v2 < 2; ++v2) {
            unsigned a0 = w8[v2], b0 = w8[2 + v2];
            asm volatile("v_permlane32_swap_b32 %0, %1" : "+v"(a0), "+v"(b0));
            bf0.u[v2] = a0; bf0.u[2 + v2] = b0;
            unsigned a1 = w8[4 + v2], b1 = w8[6 + v2];
            asm volatile("v_permlane32_swap_b32 %0, %1" : "+v"(a1), "+v"(b1));
            bf1.u[v2] = a1; bf1.u[2 + v2] = b1;
        }
        pb0 = bf0.v; pb1 = bf1.v;
    };

    stage(0, 0);
    __syncthreads();

    for (int t = 0; t < 16; ++t) {
        if (t < 15) stage(t + 1, (t + 1) & 1);
        const char* kb = mybase + (t & 1) * 16384;
        const char* vb = kb + 8192;

        // ---- S^T (32j x 32q) for BOTH q-blocks: K-frag read once ----
        f32x16 sT0, sT1;
#pragma unroll
        for (int i = 0; i < 16; ++i) { sT0[i] = 0.f; sT1[i] = 0.f; }
        __builtin_amdgcn_s_setprio(1);
#pragma unroll
        for (int kc = 0; kc < 8; ++kc) {
            int byte = (qp * 256 + kc * 32 + h * 16) ^ ((qp & 7) << 4);
            f16x8 kA = *(const f16x8*)(kb + byte);
            sT0 = MFMA32F(kA, qf0[kc], sT0);
            sT1 = MFMA32F(kA, qf1[kc], sT1);
        }
        __builtin_amdgcn_s_setprio(0);

        // ---- independent online softmax per q-block ----
        f16x8 p00, p01, p10, p11;
        softmax_pack(sT0, m0, l0, o0, p00, p01);
        softmax_pack(sT1, m1, l1, o1, p10, p11);

        // ---- O^T += V^T x P^T, V-frags read once for both q-blocks ----
        __builtin_amdgcn_s_setprio(1);
#pragma unroll
        for (int db = 0; db < 4; ++db) {
            int rowbyte = (db * 32 + qp) * 64;
            int x0 = (rowbyte + h * 16) ^ ((qp & 7) << 4);
            int x1 = (rowbyte + 32 + h * 16) ^ ((qp & 7) << 4);
            f16x8 v0 = *(const f16x8*)(vb + x0);
            f16x8 v1 = *(const f16x8*)(vb + x1);
            o0[db] = MFMA32F(v0, p00, o0[db]);
            o0[db] = MFMA32F(v1, p01, o0[db]);
            o1[db] = MFMA32F(v0, p10, o1[db]);
            o1[db] = MFMA32F(v1, p11, o1[db]);
        }
        __builtin_amdgcn_s_setprio(0);

        __syncthreads();
    }

    // ---- 4-way flash-combine across KV groups (waves with same s) ----
    float4* mls = (float4*)smem;                 // [wv][lane], 8 KB
    mls[wv * 64 + lane] = make_float4(m0, l0, m1, l1);
    __syncthreads();
    float4 q2 = mls[(wv ^ 2) * 64 + lane];
    float4 q4 = mls[(wv ^ 4) * 64 + lane];
    float4 q6 = mls[(wv ^ 6) * 64 + lane];
    float ms0 = fmaxf(fmaxf(m0, q2.x), fmaxf(q4.x, q6.x));
    float ls0 = __expf(m0 - ms0) * l0 + __expf(q2.x - ms0) * q2.y
              + __expf(q4.x - ms0) * q4.y + __expf(q6.x - ms0) * q6.y;
    float sc0 = __expf(m0 - ms0);
    float ms1 = fmaxf(fmaxf(m1, q2.z), fmaxf(q4.z, q6.z));
    float ls1 = __expf(m1 - ms1) * l1 + __expf(q2.z - ms1) * q2.w
              + __expf(q4.z - ms1) * q4.w + __expf(q6.z - ms1) * q6.w;
    float sc1 = __expf(m1 - ms1);
#pragma unroll
    for (int db = 0; db < 4; ++db)
#pragma unroll
        for (int i = 0; i < 16; ++i) { o0[db][i] *= sc0; o1[db][i] *= sc1; }
    __syncthreads();                             // mls reads done; reuse smem

    // region r = s + 2*(g>>1), 32 KB each; layout ((qb*4+db)*4+t2)*64+lane float4s
    const int r = s + 2 * (g >> 1);
    float* rg = (float*)(smem + r * 32768);
    // round A: odd groups write, even groups add
    if (g & 1) {
#pragma unroll
        for (int db = 0; db < 4; ++db)
#pragma unroll
            for (int t2 = 0; t2 < 4; ++t2) {
                *(float4*)(rg + ((db * 4 + t2) * 64 + lane) * 4) =
                    make_float4(o0[db][4*t2+0], o0[db][4*t2+1], o0[db][4*t2+2], o0[db][4*t2+3]);
                *(float4*)(rg + (((4 + db) * 4 + t2) * 64 + lane) * 4) =
                    make_float4(o1[db][4*t2+0], o1[db][4*t2+1], o1[db][4*t2+2], o1[db][4*t2+3]);
            }
    }
    __syncthreads();
    if (!(g & 1)) {
#pragma unroll
        for (int db = 0; db < 4; ++db)
#pragma unroll
            for (int t2 = 0; t2 < 4; ++t2) {
                float4 a = *(const float4*)(rg + ((db * 4 + t2) * 64 + lane) * 4);
                o0[db][4*t2+0] += a.x; o0[db][4*t2+1] += a.y;
                o0[db][4*t2+2] += a.z; o0[db][4*t2+3] += a.w;
                float4 c = *(const float4*)(rg + (((4 + db) * 4 + t2) * 64 + lane) * 4);
                o1[db][4*t2+0] += c.x; o1[db][4*t2+1] += c.y;
                o1[db][4*t2+2] += c.z; o1[db][4*t2+3] += c.w;
            }
    }
    __syncthreads();
    // round B: g==2 writes region s; g==0 adds
    float* rb = (float*)(smem + s * 32768);
    if (g == 2) {
#pragma unroll
        for (int db = 0; db < 4; ++db)
#pragma unroll
            for (int t2 = 0; t2 < 4; ++t2) {
                *(float4*)(rb + ((db * 4 + t2) * 64 + lane) * 4) =
                    make_float4(o0[db][4*t2+0], o0[db][4*t2+1], o0[db][4*t2+2], o0[db][4*t2+3]);
                *(float4*)(rb + (((4 + db) * 4 + t2) * 64 + lane) * 4) =
                    make_float4(o1[db][4*t2+0], o1[db][4*t2+1], o1[db][4*t2+2], o1[db][4*t2+3]);
            }
    }
    __syncthreads();

    // ---- epilogue: waves 0,1 (g==0) normalize, gate by Q, float4 stores ----
    if (g == 0) {
#pragma unroll
        for (int db = 0; db < 4; ++db)
#pragma unroll
            for (int t2 = 0; t2 < 4; ++t2) {
                float4 a = *(const float4*)(rb + ((db * 4 + t2) * 64 + lane) * 4);
                o0[db][4*t2+0] += a.x; o0[db][4*t2+1] += a.y;
                o0[db][4*t2+2] += a.z; o0[db][4*t2+3] += a.w;
                float4 c = *(const float4*)(rb + (((4 + db) * 4 + t2) * 64 + lane) * 4);
                o1[db][4*t2+0] += c.x; o1[db][4*t2+1] += c.y;
                o1[db][4*t2+2] += c.z; o1[db][4*t2+3] += c.w;
            }
        const float inv0 = 1.f / ls0;
        float* outr0 = Out + ((size_t)(b * S + i0 + qp)) * (2 * D) + ocol;
#pragma unroll
        for (int db = 0; db < 4; ++db)
#pragma unroll
            for (int t2 = 0; t2 < 4; ++t2) {
                int d0 = db * 32 + t2 * 8 + h * 4;
                float4 qv = *(const float4*)(qrow0 + d0);
                float4 ov;
                ov.x = o0[db][4*t2+0] * inv0 * qv.x;
                ov.y = o0[db][4*t2+1] * inv0 * qv.y;
                ov.z = o0[db][4*t2+2] * inv0 * qv.z;
                ov.w = o0[db][4*t2+3] * inv0 * qv.w;
                *(float4*)(outr0 + d0) = ov;
            }
        const float inv1 = 1.f / ls1;
        float* outr1 = Out + ((size_t)(b * S + i0 + 32 + qp)) * (2 * D) + ocol;
#pragma unroll
        for (int db = 0; db < 4; ++db)
#pragma unroll
            for (int t2 = 0; t2 < 4; ++t2) {
                int d0 = db * 32 + t2 * 8 + h * 4;
                float4 qv = *(const float4*)(qrow1 + d0);
                float4 ov;
                ov.x = o1[db][4*t2+0] * inv1 * qv.x;
                ov.y = o1[db][4*t2+1] * inv1 * qv.y;
                ov.z = o1[db][4*t2+2] * inv1 * qv.z;
                ov.w = o1[db][4*t2+3] * inv1 * qv.w;
                *(float4*)(outr1 + d0) = ov;
            }
    }
}

// ---------------- fallback (round-2 verified kernel, no workspace needed) ----------------
__global__ __launch_bounds__(256) void bimodal_attn_fb(
    const float* __restrict__ X, const float* __restrict__ Y,
    float* __restrict__ Out)
{
    const int bid = blockIdx.x;
    const int qt = bid & 31;
    const int p  = (bid >> 5) & 1;
    const int b  = bid >> 6;

    const float* Q  = p ? Y : X;
    const float* KV = p ? X : Y;
    const int ocol = p * D;

    __shared__ unsigned short Khi[64 * D];
    __shared__ unsigned short Klo[64 * D];
    __shared__ unsigned short Vt[D * 64];
    __shared__ unsigned short Psh[4][16 * 72];

    const int tid = threadIdx.x;
    const int wv = tid >> 6;
    const int lane = tid & 63;
    const int c = lane & 15;
    const int g = lane >> 4;
    const int i0 = qt * 64 + wv * 16;

    const float* qbase = Q + ((size_t)(b * S + i0 + c)) * D;
    bf16x8 qhi[4], qlo[4];
#pragma unroll
    for (int kc = 0; kc < 4; ++kc) {
        const float* qp = qbase + kc * 32 + g * 8;
        float4 f0 = *(const float4*)qp;
        float4 f1 = *(const float4*)(qp + 4);
        float fv[8] = {f0.x, f0.y, f0.z, f0.w, f1.x, f1.y, f1.z, f1.w};
        bf16x8 th, tl;
#pragma unroll
        for (int i = 0; i < 8; ++i) {
            unsigned short hh = f2b(fv[i]);
            th[i] = (short)hh;
            tl[i] = (short)f2b(fv[i] - b2f(hh));
        }
        qhi[kc] = th; qlo[kc] = tl;
    }

    f32x4 o[8];
#pragma unroll
    for (int nb = 0; nb < 8; ++nb) { o[nb][0] = 0.f; o[nb][1] = 0.f; o[nb][2] = 0.f; o[nb][3] = 0.f; }
    float m[4], l[4];
#pragma unroll
    for (int r = 0; r < 4; ++r) { m[r] = -1e30f; l[r] = 0.f; }

    const float* kvb = KV + (size_t)b * S * D;
    unsigned short* pbuf = Psh[wv];

    for (int j0 = 0; j0 < S; j0 += 64) {
#pragma unroll
        for (int t = 0; t < 4; ++t) {
            int task = tid + t * 256;
            int jr = task >> 4, sl = task & 15;
            const float* src = kvb + (size_t)(j0 + jr) * D + sl * 8;
            float4 f0 = *(const float4*)src;
            float4 f1 = *(const float4*)(src + 4);
            float fv[8] = {f0.x, f0.y, f0.z, f0.w, f1.x, f1.y, f1.z, f1.w};
            unsigned short hv[8];
            float lv[8];
#pragma unroll
            for (int i = 0; i < 8; ++i) {
                hv[i] = f2b(fv[i]);
                lv[i] = fv[i] - b2f(hv[i]);
            }
            uint4 wh, wl;
            wh.x = (unsigned int)hv[0] | ((unsigned int)hv[1] << 16);
            wh.y = (unsigned int)hv[2] | ((unsigned int)hv[3] << 16);
            wh.z = (unsigned int)hv[4] | ((unsigned int)hv[5] << 16);
            wh.w = (unsigned int)hv[6] | ((unsigned int)hv[7] << 16);
            wl.x = pack2(lv[0], lv[1]); wl.y = pack2(lv[2], lv[3]);
            wl.z = pack2(lv[4], lv[5]); wl.w = pack2(lv[6], lv[7]);
            int byte = (jr * 256 + sl * 16) ^ ((jr & 7) << 4);
            *(uint4*)((char*)Khi + byte) = wh;
            *(uint4*)((char*)Klo + byte) = wl;
        }
#pragma unroll
        for (int t = 0; t < 2; ++t) {
            int task = tid + t * 256;
            int jp = task & 31, dc = task >> 5;
            const float* s0 = kvb + (size_t)(j0 + 2 * jp) * D + dc * 8;
            const float* s1 = s0 + D;
            float4 a0 = *(const float4*)s0, a1 = *(const float4*)(s0 + 4);
            float4 b0 = *(const float4*)s1, b1 = *(const float4*)(s1 + 4);
            float av[8] = {a0.x, a0.y, a0.z, a0.w, a1.x, a1.y, a1.z, a1.w};
            float bv[8] = {b0.x, b0.y, b0.z, b0.w, b1.x, b1.y, b1.z, b1.w};
#pragma unroll
            for (int i = 0; i < 8; ++i) {
                int d = dc * 8 + i;
                int byte = (d * 128 + jp * 4) ^ ((d & 7) << 4);
                *(unsigned int*)((char*)Vt + byte) = pack2(av[i], bv[i]);
            }
        }
        __syncthreads();

        f32x4 sF[4];
#pragma unroll
        for (int nb = 0; nb < 4; ++nb) {
            f32x4 acc; acc[0] = 0.f; acc[1] = 0.f; acc[2] = 0.f; acc[3] = 0.f;
#pragma unroll
            for (int kc = 0; kc < 4; ++kc) {
                int row = nb * 16 + c;
                int byte = (row * 256 + (kc * 32 + g * 8) * 2) ^ ((row & 7) << 4);
                bf16x8 kh = *(const bf16x8*)((char*)Khi + byte);
                bf16x8 kl = *(const bf16x8*)((char*)Klo + byte);
                acc = MFMA16B(qhi[kc], kh, acc);
                acc = MFMA16B(qhi[kc], kl, acc);
                acc = MFMA16B(qlo[kc], kh, acc);
            }
            sF[nb] = acc;
        }

#pragma unroll
        for (int r = 0; r < 4; ++r) {
            float v = fmaxf(fmaxf(sF[0][r], sF[1][r]), fmaxf(sF[2][r], sF[3][r]));
            v = fmaxf(v, __shfl_xor(v, 1));
            v = fmaxf(v, __shfl_xor(v, 2));
            v = fmaxf(v, __shfl_xor(v, 4));
            v = fmaxf(v, __shfl_xor(v, 8));
            float mn = fmaxf(m[r], v);
            float alpha = __expf(m[r] - mn);
            m[r] = mn;
            float rs = 0.f;
#pragma unroll
            for (int nb = 0; nb < 4; ++nb) {
                float pv = __expf(sF[nb][r] - mn);
                sF[nb][r] = pv;
                rs += pv;
            }
            rs += __shfl_xor(rs, 1);
            rs += __shfl_xor(rs, 2);
            rs += __shfl_xor(rs, 4);
            rs += __shfl_xor(rs, 8);
            l[r] = l[r] * alpha + rs;
#pragma unroll
            for (int nb = 0; nb < 8; ++nb) o[nb][r] *= alpha;
        }

#pragma unroll
        for (int nb = 0; nb < 4; ++nb)
#pragma unroll
            for (int r = 0; r < 4; ++r)
                pbuf[(g * 4 + r) * 72 + nb * 16 + c] = f2b(sF[nb][r]);

        bf16x8 pa[2];
#pragma unroll
        for (int kc = 0; kc < 2; ++kc)
            pa[kc] = *(const bf16x8*)(pbuf + c * 72 + kc * 32 + g * 8);

#pragma unroll
        for (int nb = 0; nb < 8; ++nb) {
#pragma unroll
            for (int kc = 0; kc < 2; ++kc) {
                int d = nb * 16 + c;
                int byte = (d * 128 + (kc * 32 + g * 8) * 2) ^ ((d & 7) << 4);
                bf16x8 vf = *(const bf16x8*)((char*)Vt + byte);
                o[nb] = MFMA16B(pa[kc], vf, o[nb]);
            }
        }
        __syncthreads();
    }

    float* outb = Out + ((size_t)(b * S + i0)) * (2 * D) + ocol;
    const float* qg = Q + (size_t)(b * S + i0) * D;
#pragma unroll
    for (int r = 0; r < 4; ++r) {
        int row = g * 4 + r;
        float inv = 1.f / l[r];
#pragma unroll
        for (int nb = 0; nb < 8; ++nb) {
            int col = nb * 16 + c;
            float qv = qg[(size_t)row * D + col];
            outb[(size_t)row * (2 * D) + col] = o[nb][r] * inv * qv;
        }
    }
}

extern "C" void kernel_launch(void* const* d_in, const int* in_sizes, int n_in,
                              void* d_out, int out_size, void* d_ws, size_t ws_size,
                              hipStream_t stream) {
    const float* x = (const float*)d_in[0];
    const float* y = (const float*)d_in[1];
    float* out = (float*)d_out;
    const size_t need = 4ull * 8 * S * D * 2;   // 16 MB fp16 staging
    if (ws_size >= need) {
        hipLaunchKernelGGL(bimodal_prep5, dim3(1024), dim3(256), 0, stream,
                           x, y, (unsigned short*)d_ws);
        hipLaunchKernelGGL(bimodal_attn_v9, dim3(256), dim3(512), 0, stream,
                           x, y, (const unsigned short*)d_ws, out);
    } else {
        hipLaunchKernelGGL(bimodal_attn_fb, dim3(512), dim3(256), 0, stream, x, y, out);
    }
}

// Round 16
// 64.173 us; speedup vs baseline: 1.1260x; 1.0507x over previous
//
#include <hip/hip_runtime.h>
#include <hip/hip_bf16.h>

typedef __attribute__((ext_vector_type(8))) short bf16x8;
typedef __attribute__((ext_vector_type(8))) _Float16 f16x8;
typedef __attribute__((ext_vector_type(4))) float f32x4;
typedef __attribute__((ext_vector_type(16))) float f32x16;

#define MFMA16B(a, b, c) __builtin_amdgcn_mfma_f32_16x16x32_bf16(a, b, c, 0, 0, 0)
#define MFMA32F(a, b, c) __builtin_amdgcn_mfma_f32_32x32x16_f16(a, b, c, 0, 0, 0)

static constexpr int S = 2048;
static constexpr int D = 128;

// ---------------- helpers ----------------
__device__ inline unsigned short f2b(float f) {      // fp32->bf16 RNE
    union { float f; unsigned int u; } v; v.f = f;
    unsigned int u = v.u;
    return (unsigned short)((u + 0x7FFFu + ((u >> 16) & 1u)) >> 16);
}
__device__ inline float b2f(unsigned short h) {
    union { unsigned int u; float f; } v; v.u = ((unsigned int)h) << 16;
    return v.f;
}
__device__ inline unsigned int pack2(float a, float b) {
    return (unsigned int)f2b(a) | ((unsigned int)f2b(b) << 16);
}
__device__ inline unsigned int pkh(float a, float b) {  // fp32->fp16 RNE pair
    union { _Float16 h; unsigned short u; } ua, ub;
    ua.h = (_Float16)a; ub.h = (_Float16)b;
    return (unsigned int)ua.u | ((unsigned int)ub.u << 16);
}

// async 16B/lane global->LDS copy (CK-style integer AS reinterpret)
__device__ __forceinline__ void gload16(const void* g, void* l) {
    __builtin_amdgcn_global_load_lds(
        (const __attribute__((address_space(1))) unsigned int*)(unsigned long long)(g),
        (__attribute__((address_space(3))) unsigned int*)(unsigned int)(unsigned long long)(l),
        16, 0, 0);
}

// ---------------- prep: fp32 -> fp16 images for the 32x32 MFMA kernel ------------
// ws (ushort units): [mat(0=X,1=Y)][role(0=K,1=VT)], each 8*S*D elems.
// Per (b, t32) tile (8 KB each, 64 tiles per b):
//   K  image: byte(j,d pair cp) = j*256 + cp*4,   XOR ((j&7)<<4)   (j=0..31, cp=0..63)
//   VT image: byte(d, j pair jp) = d*64 + jp*4,   XOR ((d&7)<<4)   (d=0..127, jp=0..15)
__global__ __launch_bounds__(256) void bimodal_prep5(
    const float* __restrict__ X, const float* __restrict__ Y,
    unsigned short* __restrict__ WS)
{
    const int bid = blockIdx.x;          // [mat(2)][b(8)][t(64)]
    const int t = bid & 63;
    const int b = (bid >> 6) & 7;
    const int mat = bid >> 9;
    const float* src = mat ? Y : X;
    char* kf = (char*)(WS + (size_t)(mat * 2 + 0) * (8ull * S * D)) + (size_t)(b * 64 + t) * 8192;
    char* vt = (char*)(WS + (size_t)(mat * 2 + 1) * (8ull * S * D)) + (size_t)(b * 64 + t) * 8192;

    __shared__ float ftile[32][129];
    const int tid = threadIdx.x;
    const float* tsrc = src + ((size_t)(b * S + t * 32)) * D;
#pragma unroll
    for (int it = 0; it < 4; ++it) {
        int idx = tid + it * 256;        // 1024 float4 chunks
        int row = idx >> 5, ch = idx & 31;
        float4 v = *(const float4*)(tsrc + (size_t)row * D + ch * 4);
        ftile[row][ch * 4 + 0] = v.x; ftile[row][ch * 4 + 1] = v.y;
        ftile[row][ch * 4 + 2] = v.z; ftile[row][ch * 4 + 3] = v.w;
    }
    __syncthreads();
#pragma unroll
    for (int it = 0; it < 8; ++it) {
        int w = tid + it * 256;          // 2048 dwords: K row-major
        int row = w >> 6, cp = w & 63;
        unsigned int d = pkh(ftile[row][2 * cp], ftile[row][2 * cp + 1]);
        int byte = (row * 256 + cp * 4) ^ ((row & 7) << 4);
        *(unsigned int*)(kf + byte) = d;
    }
#pragma unroll
    for (int it = 0; it < 8; ++it) {
        int w = tid + it * 256;          // 2048 dwords: V transposed
        int dd = w >> 4, jp = w & 15;
        unsigned int d = pkh(ftile[2 * jp][dd], ftile[2 * jp + 1][dd]);
        int byte = (dd * 64 + jp * 4) ^ ((dd & 7) << 4);
        *(unsigned int*)(vt + byte) = d;
    }
}

// ---------------- main: 32x32x16 swapped-QK^T flash attention, pair-tile steps ----
// 256 blocks x 512 threads (8 waves). Waves 0-3 (grp 0): tiles 0..31;
// waves 4-7 (grp 1): tiles 32..63. 16 steps x 2 tiles; flash-combine (wv, wv^4).
__global__ __launch_bounds__(512) void bimodal_attn_v7(
    const float* __restrict__ X, const float* __restrict__ Y,
    const unsigned short* __restrict__ WS, float* __restrict__ Out)
{
    const int orig = blockIdx.x;
    const int wg = (orig & 7) * 32 + (orig >> 3);   // XCD-aware swizzle (256 = 8*32)
    const int qt = wg & 15;
    const int p  = (wg >> 4) & 1;
    const int b  = wg >> 5;

    const float* Q = p ? Y : X;
    const int kvmat = p ? 0 : 1;
    const int ocol = p * D;

    __shared__ __align__(16) char smem[131072];  // 2 grp x 2 buf x (K0|K1|V0|V1 = 32 KB)

    const int tid = threadIdx.x;
    const int wv = tid >> 6;
    const int lane = tid & 63;
    const int qp = lane & 31;          // q column / A-frag row
    const int h = lane >> 5;           // lane half
    const int grp = wv >> 2;           // KV group
    const int qb = wv & 3;             // q-block
    const int i0 = qt * 128 + qb * 32;

    // Q B-frags (32x32x16): lane supplies Q[qp][16*kc + 8*h + i]
    const float* qrow = Q + ((size_t)(b * S + i0 + qp)) * D;
    f16x8 qf[8];
#pragma unroll
    for (int kc = 0; kc < 8; ++kc) {
        const float* qpp = qrow + kc * 16 + h * 8;
        float4 f0 = *(const float4*)qpp;
        float4 f1 = *(const float4*)(qpp + 4);
        f16x8 tq;
        tq[0] = (_Float16)f0.x; tq[1] = (_Float16)f0.y; tq[2] = (_Float16)f0.z; tq[3] = (_Float16)f0.w;
        tq[4] = (_Float16)f1.x; tq[5] = (_Float16)f1.y; tq[6] = (_Float16)f1.z; tq[7] = (_Float16)f1.w;
        qf[kc] = tq;
    }

    f32x16 o[4];
#pragma unroll
    for (int db = 0; db < 4; ++db)
#pragma unroll
        for (int i = 0; i < 16; ++i) o[db][i] = 0.f;
    float m = -1e30f, l = 0.f;

    const char* kfb = (const char*)(WS + (size_t)(kvmat * 2 + 0) * (8ull * S * D)) + (size_t)b * (S * D * 2);
    const char* vtb = (const char*)(WS + (size_t)(kvmat * 2 + 1) * (8ull * S * D)) + (size_t)b * (S * D * 2);
    const int gl = qb * 64 + lane;     // 0..255 within group
    char* mybase = smem + grp * 65536;

    auto stage = [&](int ps, int bi) {
        char* kb = mybase + bi * 32768;
        const char* kt = kfb + (size_t)(32 * grp + 2 * ps) * 8192;   // 16 KB (2 K tiles)
        const char* vp = vtb + (size_t)(32 * grp + 2 * ps) * 8192;   // 16 KB (2 V tiles)
#pragma unroll
        for (int i = 0; i < 4; ++i)
            gload16(kt + gl * 16 + i * 4096, kb + gl * 16 + i * 4096);
#pragma unroll
        for (int i = 0; i < 4; ++i)
            gload16(vp + gl * 16 + i * 4096, kb + 16384 + gl * 16 + i * 4096);
    };

    auto qkt = [&](const char* kb) {
        f32x16 sT;
#pragma unroll
        for (int i = 0; i < 16; ++i) sT[i] = 0.f;
#pragma unroll
        for (int kc = 0; kc < 8; ++kc) {
            int byte = (qp * 256 + kc * 32 + h * 16) ^ ((qp & 7) << 4);
            f16x8 kA = *(const f16x8*)(kb + byte);
            sT = MFMA32F(kA, qf[kc], sT);
        }
        return sT;
    };

    auto smpv = [&](f32x16& sT, const char* vb) {
        float pmax = sT[0];
#pragma unroll
        for (int i = 1; i < 16; ++i) pmax = fmaxf(pmax, sT[i]);
        pmax = fmaxf(pmax, __shfl_xor(pmax, 32));
        if (!__all(pmax - m <= 8.f)) {       // T13 defer-max
            float mn = fmaxf(m, pmax);
            float alpha = __expf(m - mn);
            m = mn; l *= alpha;
#pragma unroll
            for (int db = 0; db < 4; ++db)
#pragma unroll
                for (int i = 0; i < 16; ++i) o[db][i] *= alpha;
        }
        float rs = 0.f;
#pragma unroll
        for (int i = 0; i < 16; ++i) { sT[i] = __expf(sT[i] - m); rs += sT[i]; }
        rs += __shfl_xor(rs, 32);
        l += rs;

        // pack P pairs; build PV B-frags with permlane32_swap (T12)
        unsigned w8[8];
#pragma unroll
        for (int t2 = 0; t2 < 4; ++t2) {
            w8[2 * t2]     = pkh(sT[4 * t2 + 0], sT[4 * t2 + 1]);
            w8[2 * t2 + 1] = pkh(sT[4 * t2 + 2], sT[4 * t2 + 3]);
        }
        union { unsigned u[4]; f16x8 v; } bf0, bf1;
#pragma unroll
        for (int v2 = 0; v2 < 2; ++v2) {
            unsigned a0 = w8[v2], b0 = w8[2 + v2];
            asm volatile("v_permlane32_swap_b32 %0, %1" : "+v"(a0), "+v"(b0));
            bf0.u[v2] = a0; bf0.u[2 + v2] = b0;
            unsigned a1 = w8[4 + v2], b1 = w8[6 + v2];
            asm volatile("v_permlane32_swap_b32 %0, %1" : "+v"(a1), "+v"(b1));
            bf1.u[v2] = a1; bf1.u[2 + v2] = b1;
        }

        __builtin_amdgcn_s_setprio(1);
#pragma unroll
        for (int db = 0; db < 4; ++db) {
            int rowbyte = (db * 32 + qp) * 64;
            int x0 = (rowbyte + h * 16) ^ ((qp & 7) << 4);
            int x1 = (rowbyte + 32 + h * 16) ^ ((qp & 7) << 4);
            f16x8 v0 = *(const f16x8*)(vb + x0);
            f16x8 v1 = *(const f16x8*)(vb + x1);
            o[db] = MFMA32F(v0, bf0.v, o[db]);
            o[db] = MFMA32F(v1, bf1.v, o[db]);
        }
        __builtin_amdgcn_s_setprio(0);
    };

    stage(0, 0);
    __syncthreads();

    for (int s = 0; s < 16; ++s) {
        if (s < 15) stage(s + 1, (s + 1) & 1);
        const char* kb = mybase + (s & 1) * 32768;

        __builtin_amdgcn_s_setprio(1);
        f32x16 s0 = qkt(kb);            // tile 2s
        f32x16 s1 = qkt(kb + 8192);     // tile 2s+1
        __builtin_amdgcn_s_setprio(0);

        smpv(s0, kb + 16384);           // SM(t0) overlaps QK(t1) MFMAs; PV(t0)
        smpv(s1, kb + 24576);           // SM(t1) overlaps PV(t0) MFMAs; PV(t1)

        __syncthreads();
    }

    // ---- flash-combine across wave pairs (wv, wv^4) ----
    {
        float2* mlp = (float2*)(smem + wv * 512);
        mlp[lane] = make_float2(m, l);
    }
    __syncthreads();
    float2 pml = ((float2*)(smem + (wv ^ 4) * 512))[lane];
    float mstar = fmaxf(m, pml.x);
    float sc = __expf(m - mstar);
    float lstar = sc * l + __expf(pml.x - mstar) * pml.y;
#pragma unroll
    for (int db = 0; db < 4; ++db)
#pragma unroll
        for (int i = 0; i < 16; ++i) o[db][i] *= sc;
    __syncthreads();

    // conflict-free transposed exchange: ob[qb][i][lane]
    float* ob = (float*)(smem + 4096);
#pragma unroll
    for (int db = 0; db < 4; ++db) {
        if (grp == 1) {
#pragma unroll
            for (int i = 0; i < 16; ++i) ob[qb * 1024 + i * 64 + lane] = o[db][i];
        }
        __syncthreads();
        if (grp == 0) {
#pragma unroll
            for (int i = 0; i < 16; ++i) o[db][i] += ob[qb * 1024 + i * 64 + lane];
        }
        __syncthreads();
    }

    // ---- epilogue (group 0 only): normalize, gate by Q, float4 stores ----
    if (grp == 0) {
        const float invl = 1.f / lstar;
        float* outr = Out + ((size_t)(b * S + i0 + qp)) * (2 * D) + ocol;
#pragma unroll
        for (int db = 0; db < 4; ++db)
#pragma unroll
            for (int t2 = 0; t2 < 4; ++t2) {
                int d0 = db * 32 + t2 * 8 + h * 4;
                float4 qv = *(const float4*)(qrow + d0);
                float4 ov;
                ov.x = o[db][4 * t2 + 0] * invl * qv.x;
                ov.y = o[db][4 * t2 + 1] * invl * qv.y;
                ov.z = o[db][4 * t2 + 2] * invl * qv.z;
                ov.w = o[db][4 * t2 + 3] * invl * qv.w;
                *(float4*)(outr + d0) = ov;
            }
    }
}

// ---------------- fallback (round-2 verified kernel, no workspace needed) ----------------
__global__ __launch_bounds__(256) void bimodal_attn_fb(
    const float* __restrict__ X, const float* __restrict__ Y,
    float* __restrict__ Out)
{
    const int bid = blockIdx.x;
    const int qt = bid & 31;
    const int p  = (bid >> 5) & 1;
    const int b  = bid >> 6;

    const float* Q  = p ? Y : X;
    const float* KV = p ? X : Y;
    const int ocol = p * D;

    __shared__ unsigned short Khi[64 * D];
    __shared__ unsigned short Klo[64 * D];
    __shared__ unsigned short Vt[D * 64];
    __shared__ unsigned short Psh[4][16 * 72];

    const int tid = threadIdx.x;
    const int wv = tid >> 6;
    const int lane = tid & 63;
    const int c = lane & 15;
    const int g = lane >> 4;
    const int i0 = qt * 64 + wv * 16;

    const float* qbase = Q + ((size_t)(b * S + i0 + c)) * D;
    bf16x8 qhi[4], qlo[4];
#pragma unroll
    for (int kc = 0; kc < 4; ++kc) {
        const float* qp = qbase + kc * 32 + g * 8;
        float4 f0 = *(const float4*)qp;
        float4 f1 = *(const float4*)(qp + 4);
        float fv[8] = {f0.x, f0.y, f0.z, f0.w, f1.x, f1.y, f1.z, f1.w};
        bf16x8 th, tl;
#pragma unroll
        for (int i = 0; i < 8; ++i) {
            unsigned short hh = f2b(fv[i]);
            th[i] = (short)hh;
            tl[i] = (short)f2b(fv[i] - b2f(hh));
        }
        qhi[kc] = th; qlo[kc] = tl;
    }

    f32x4 o[8];
#pragma unroll
    for (int nb = 0; nb < 8; ++nb) { o[nb][0] = 0.f; o[nb][1] = 0.f; o[nb][2] = 0.f; o[nb][3] = 0.f; }
    float m[4], l[4];
#pragma unroll
    for (int r = 0; r < 4; ++r) { m[r] = -1e30f; l[r] = 0.f; }

    const float* kvb = KV + (size_t)b * S * D;
    unsigned short* pbuf = Psh[wv];

    for (int j0 = 0; j0 < S; j0 += 64) {
#pragma unroll
        for (int t = 0; t < 4; ++t) {
            int task = tid + t * 256;
            int jr = task >> 4, sl = task & 15;
            const float* src = kvb + (size_t)(j0 + jr) * D + sl * 8;
            float4 f0 = *(const float4*)src;
            float4 f1 = *(const float4*)(src + 4);
            float fv[8] = {f0.x, f0.y, f0.z, f0.w, f1.x, f1.y, f1.z, f1.w};
            unsigned short hv[8];
            float lv[8];
#pragma unroll
            for (int i = 0; i < 8; ++i) {
                hv[i] = f2b(fv[i]);
                lv[i] = fv[i] - b2f(hv[i]);
            }
            uint4 wh, wl;
            wh.x = (unsigned int)hv[0] | ((unsigned int)hv[1] << 16);
            wh.y = (unsigned int)hv[2] | ((unsigned int)hv[3] << 16);
            wh.z = (unsigned int)hv[4] | ((unsigned int)hv[5] << 16);
            wh.w = (unsigned int)hv[6] | ((unsigned int)hv[7] << 16);
            wl.x = pack2(lv[0], lv[1]); wl.y = pack2(lv[2], lv[3]);
            wl.z = pack2(lv[4], lv[5]); wl.w = pack2(lv[6], lv[7]);
            int byte = (jr * 256 + sl * 16) ^ ((jr & 7) << 4);
            *(uint4*)((char*)Khi + byte) = wh;
            *(uint4*)((char*)Klo + byte) = wl;
        }
#pragma unroll
        for (int t = 0; t < 2; ++t) {
            int task = tid + t * 256;
            int jp = task & 31, dc = task >> 5;
            const float* s0 = kvb + (size_t)(j0 + 2 * jp) * D + dc * 8;
            const float* s1 = s0 + D;
            float4 a0 = *(const float4*)s0, a1 = *(const float4*)(s0 + 4);
            float4 b0 = *(const float4*)s1, b1 = *(const float4*)(s1 + 4);
            float av[8] = {a0.x, a0.y, a0.z, a0.w, a1.x, a1.y, a1.z, a1.w};
            float bv[8] = {b0.x, b0.y, b0.z, b0.w, b1.x, b1.y, b1.z, b1.w};
#pragma unroll
            for (int i = 0; i < 8; ++i) {
                int d = dc * 8 + i;
                int byte = (d * 128 + jp * 4) ^ ((d & 7) << 4);
                *(unsigned int*)((char*)Vt + byte) = pack2(av[i], bv[i]);
            }
        }
        __syncthreads();

        f32x4 sF[4];
#pragma unroll
        for (int nb = 0; nb < 4; ++nb) {
            f32x4 acc; acc[0] = 0.f; acc[1] = 0.f; acc[2] = 0.f; acc[3] = 0.f;
#pragma unroll
            for (int kc = 0; kc < 4; ++kc) {
                int row = nb * 16 + c;
                int byte = (row * 256 + (kc * 32 + g * 8) * 2) ^ ((row & 7) << 4);
                bf16x8 kh = *(const bf16x8*)((char*)Khi + byte);
                bf16x8 kl = *(const bf16x8*)((char*)Klo + byte);
                acc = MFMA16B(qhi[kc], kh, acc);
                acc = MFMA16B(qhi[kc], kl, acc);
                acc = MFMA16B(qlo[kc], kh, acc);
            }
            sF[nb] = acc;
        }

#pragma unroll
        for (int r = 0; r < 4; ++r) {
            float v = fmaxf(fmaxf(sF[0][r], sF[1][r]), fmaxf(sF[2][r], sF[3][r]));
            v = fmaxf(v, __shfl_xor(v, 1));
            v = fmaxf(v, __shfl_xor(v, 2));
            v = fmaxf(v, __shfl_xor(v, 4));
            v = fmaxf(v, __shfl_xor(v, 8));
            float mn = fmaxf(m[r], v);
            float alpha = __expf(m[r] - mn);
            m[r] = mn;
            float rs = 0.f;
#pragma unroll
            for (int nb = 0; nb < 4; ++nb) {
                float pv = __expf(sF[nb][r] - mn);
                sF[nb][r] = pv;
                rs += pv;
            }
            rs += __shfl_xor(rs, 1);
            rs += __shfl_xor(rs, 2);
            rs += __shfl_xor(rs, 4);
            rs += __shfl_xor(rs, 8);
            l[r] = l[r] * alpha + rs;
#pragma unroll
            for (int nb = 0; nb < 8; ++nb) o[nb][r] *= alpha;
        }

#pragma unroll
        for (int nb = 0; nb < 4; ++nb)
#pragma unroll
            for (int r = 0; r < 4; ++r)
                pbuf[(g * 4 + r) * 72 + nb * 16 + c] = f2b(sF[nb][r]);

        bf16x8 pa[2];
#pragma unroll
        for (int kc = 0; kc < 2; ++kc)
            pa[kc] = *(const bf16x8*)(pbuf + c * 72 + kc * 32 + g * 8);

#pragma unroll
        for (int nb = 0; nb < 8; ++nb) {
#pragma unroll
            for (int kc = 0; kc < 2; ++kc) {
                int d = nb * 16 + c;
                int byte = (d * 128 + (kc * 32 + g * 8) * 2) ^ ((d & 7) << 4);
                bf16x8 vf = *(const bf16x8*)((char*)Vt + byte);
                o[nb] = MFMA16B(pa[kc], vf, o[nb]);
            }
        }
        __syncthreads();
    }

    float* outb = Out + ((size_t)(b * S + i0)) * (2 * D) + ocol;
    const float* qg = Q + (size_t)(b * S + i0) * D;
#pragma unroll
    for (int r = 0; r < 4; ++r) {
        int row = g * 4 + r;
        float inv = 1.f / l[r];
#pragma unroll
        for (int nb = 0; nb < 8; ++nb) {
            int col = nb * 16 + c;
            float qv = qg[(size_t)row * D + col];
            outb[(size_t)row * (2 * D) + col] = o[nb][r] * inv * qv;
        }
    }
}

extern "C" void kernel_launch(void* const* d_in, const int* in_sizes, int n_in,
                              void* d_out, int out_size, void* d_ws, size_t ws_size,
                              hipStream_t stream) {
    const float* x = (const float*)d_in[0];
    const float* y = (const float*)d_in[1];
    float* out = (float*)d_out;
    const size_t need = 4ull * 8 * S * D * 2;   // 16 MB fp16 staging
    if (ws_size >= need) {
        hipLaunchKernelGGL(bimodal_prep5, dim3(1024), dim3(256), 0, stream,
                           x, y, (unsigned short*)d_ws);
        hipLaunchKernelGGL(bimodal_attn_v7, dim3(256), dim3(512), 0, stream,
                           x, y, (const unsigned short*)d_ws, out);
    } else {
        hipLaunchKernelGGL(bimodal_attn_fb, dim3(512), dim3(256), 0, stream, x, y, out);
    }
}